// Round 4
// baseline (290.929 us; speedup 1.0000x reference)
//
#include <hip/hip_runtime.h>

typedef unsigned short u16;
typedef unsigned int u32;

#define LDSW 68  // padded fp32 row stride for xs/ws

__device__ __forceinline__ float bflo(u32 v){ union{float f;u32 i;}c; c.i = v<<16; return c.f; }
__device__ __forceinline__ float bfhi(u32 v){ union{float f;u32 i;}c; c.i = v & 0xFFFF0000u; return c.f; }
__device__ __forceinline__ u16 f2bf(float f){
    union{float f;u32 i;}c; c.f = f;
    u32 i = c.i;
    return (u16)((i + 0x7FFFu + ((i>>16)&1u)) >> 16);  // RNE
}

__device__ __forceinline__ void load16g(const float* __restrict__ g, float* __restrict__ dst){
    const float4* p = (const float4*)g;
    float4 a = p[0], b = p[1], c = p[2], d = p[3];
    *(float4*)&dst[0]  = a;
    *(float4*)&dst[4]  = b;
    *(float4*)&dst[8]  = c;
    *(float4*)&dst[12] = d;
}

// 1-row x 16-col scheme (q only; result stays in registers)
__device__ __forceinline__ void mm_row16(const float* __restrict__ xrow,
                                         const float* __restrict__ wc,
                                         float* __restrict__ acc){
    #pragma unroll
    for (int d = 0; d < 64; d += 4) {
        float4 xv = *(const float4*)&xrow[d];
        float xf[4] = {xv.x, xv.y, xv.z, xv.w};
        #pragma unroll
        for (int dd = 0; dd < 4; ++dd) {
            const float* wr = wc + (d+dd)*LDSW;
            #pragma unroll
            for (int j = 0; j < 16; j += 4) {
                float4 wv = *(const float4*)&wr[j];
                acc[j+0] = fmaf(xf[dd], wv.x, acc[j+0]);
                acc[j+1] = fmaf(xf[dd], wv.y, acc[j+1]);
                acc[j+2] = fmaf(xf[dd], wv.z, acc[j+2]);
                acc[j+3] = fmaf(xf[dd], wv.w, acc[j+3]);
            }
        }
    }
}

// 4-row x 4-col scheme: thread (rg,cg) computes rows {rg,rg+16,rg+32,rg+48},
// cols 4cg..4cg+3. W reads amortize over 4 rows: 128 b128 total per call.
__device__ __forceinline__ void mm4x4(const float* __restrict__ xbase,
                                      const float* __restrict__ wcol,  // &ws[4*cg]
                                      int rg, float acc[4][4]){
    #pragma unroll
    for (int k = 0; k < 64; k += 4) {
        float w_[4][4];
        #pragma unroll
        for (int kk = 0; kk < 4; ++kk) {
            float4 wv = *(const float4*)&wcol[(k+kk)*LDSW];
            w_[kk][0]=wv.x; w_[kk][1]=wv.y; w_[kk][2]=wv.z; w_[kk][3]=wv.w;
        }
        #pragma unroll
        for (int r = 0; r < 4; ++r) {
            float4 xv = *(const float4*)&xbase[(rg + 16*r)*LDSW + k];
            float xf[4] = {xv.x, xv.y, xv.z, xv.w};
            #pragma unroll
            for (int kk = 0; kk < 4; ++kk) {
                #pragma unroll
                for (int c = 0; c < 4; ++c)
                    acc[r][c] = fmaf(xf[kk], w_[kk][c], acc[r][c]);
            }
        }
    }
}

__device__ __forceinline__ void store4bf(u16* __restrict__ dst, const float a[4]){
    uint2 v;
    v.x = (u32)f2bf(a[0]) | ((u32)f2bf(a[1]) << 16);
    v.y = (u32)f2bf(a[2]) | ((u32)f2bf(a[3]) << 16);
    *(uint2*)dst = v;
}

__global__ __launch_bounds__(256, 3) void attn_fused_kernel(
    const float* __restrict__ x, const float* __restrict__ pos, const float* __restrict__ strength,
    const int* __restrict__ embed_id,
    const float* __restrict__ Wq, const float* __restrict__ Wk,
    const float* __restrict__ pW1, const float* __restrict__ pb1,
    const float* __restrict__ pW2, const float* __restrict__ pb2,
    const float* __restrict__ hW, const float* __restrict__ hb,
    const float* __restrict__ gate, const float* __restrict__ embeds,
    const float* __restrict__ oW, const float* __restrict__ ob,
    const float* __restrict__ sW, const float* __restrict__ sb,
    float* __restrict__ out)
{
    // LDS budget: 17408+17408+8192+8192+1024+1024+1024+256 = 54528 B -> 3 blocks/CU
    __shared__ __align__(16) float xs[64*LDSW];   // x fp32; reused as context
    __shared__ __align__(16) float ws[64*LDSW];   // weight buffer (Wq -> Wk -> E^T -> out_W)
    __shared__ __align__(16) u16  ksh[64*64];     // k bf16, stride 64
    __shared__ __align__(16) u16  vsh[64*64];     // v bf16, stride 64
    __shared__ __align__(16) float t_lds[4][64];
    __shared__ __align__(16) float pattn[4][64];
    __shared__ __align__(16) float sp[4][64];
    __shared__ __align__(16) float s64[64];

    const int t  = threadIdx.x;
    const int b  = blockIdx.x;
    const int n  = t >> 2;       // attention row 0..63
    const int hq = t & 3;        // head / col-quarter
    const int c0 = hq << 4;      // column base (attention scheme)
    const int cg = t & 15;       // 4x4 scheme: col group (cols 4cg..4cg+3)
    const int rg = t >> 4;       // 4x4 scheme: rows {rg, rg+16, rg+32, rg+48}

    // ---- Phase 1: stage x, strength partials, pos MLP ----
    load16g(x + ((size_t)b*64 + n)*64 + c0, &xs[n*LDSW + c0]);

    {   // s64[d] = strength @ str_W[:,d]; 4 partial slices of 128
        const int d = t & 63, part = t >> 6;
        const float* w = sW + part*128*64 + d;
        const float* s = strength + part*128;
        float acc = 0.f;
        #pragma unroll 8
        for (int i = 0; i < 128; ++i) acc = fmaf(s[i], w[i*64], acc);
        sp[part][d] = acc;
    }

    if (t < 64) {  // pos MLP: p = relu(pos@W1+b1)@W2+b2 ; t[n,h] = p . head_W[:,h]
        float pv[4], h1[4], p8[8];
        const float* gp = pos + ((size_t)b*64 + t)*4;
        #pragma unroll
        for (int i = 0; i < 4; ++i) pv[i] = gp[i];
        #pragma unroll
        for (int j = 0; j < 4; ++j){
            float a = pb1[j];
            #pragma unroll
            for (int i = 0; i < 4; ++i) a = fmaf(pv[i], pW1[i*4+j], a);
            h1[j] = fmaxf(a, 0.f);
        }
        #pragma unroll
        for (int f = 0; f < 8; ++f){
            float a = pb2[f];
            #pragma unroll
            for (int j = 0; j < 4; ++j) a = fmaf(h1[j], pW2[j*8+f], a);
            p8[f] = a;
        }
        #pragma unroll
        for (int h = 0; h < 4; ++h){
            float a = 0.f;
            #pragma unroll
            for (int f = 0; f < 8; ++f) a = fmaf(p8[f], hW[f*4+h], a);
            t_lds[h][t] = a;
        }
    }
    __syncthreads();

    // ---- Phase 2: s64 reduce; pos_attn (q-independent); load Wq ----
    if (t < 64) s64[t] = sp[0][t] + sp[1][t] + sp[2][t] + sp[3][t] + sb[t];
    {
        const int h = t >> 6, k = t & 63;
        float v0 = -t_lds[h][k];
        float m = v0;
        #pragma unroll
        for (int off = 32; off; off >>= 1) m = fmaxf(m, __shfl_xor(m, off));
        float e = __expf(v0 - m);
        float ssum = e;
        #pragma unroll
        for (int off = 32; off; off >>= 1) ssum += __shfl_xor(ssum, off);
        pattn[h][k] = e / ssum;
    }
    load16g(Wq + n*64 + c0, &ws[n*LDSW + c0]);
    __syncthreads();

    // ---- Phase 3: q = x @ Wq (stays in registers, attention mapping) ----
    float qr[16];
    #pragma unroll
    for (int j = 0; j < 16; ++j) qr[j] = 0.f;
    mm_row16(&xs[n*LDSW], &ws[c0], qr);
    __syncthreads();

    // ---- Phase 4: load Wk ----
    load16g(Wk + n*64 + c0, &ws[n*LDSW + c0]);
    __syncthreads();

    // ---- Phase 5: k = x @ Wk -> ksh bf16 (4x4 scheme) ----
    {
        float acc[4][4];
        #pragma unroll
        for (int r = 0; r < 4; ++r)
            #pragma unroll
            for (int c = 0; c < 4; ++c) acc[r][c] = 0.f;
        mm4x4(xs, &ws[4*cg], rg, acc);
        #pragma unroll
        for (int r = 0; r < 4; ++r)
            store4bf(&ksh[(rg + 16*r)*64 + 4*cg], acc[r]);
    }
    __syncthreads();

    // ---- Phase 6: load E^T (v = x @ E^T) ----
    {
        const float* ge = embeds + (size_t)(*embed_id)*4096 + n*64 + c0;
        float tv[16];
        load16g(ge, tv);
        #pragma unroll
        for (int j = 0; j < 16; ++j) ws[(c0+j)*LDSW + n] = tv[j];
    }
    __syncthreads();

    // ---- Phase 7: v = x @ E^T + s64 -> vsh bf16 (4x4 scheme) ----
    {
        float acc[4][4];
        #pragma unroll
        for (int r = 0; r < 4; ++r)
            #pragma unroll
            for (int c = 0; c < 4; ++c) acc[r][c] = s64[4*cg + c];
        mm4x4(xs, &ws[4*cg], rg, acc);
        #pragma unroll
        for (int r = 0; r < 4; ++r)
            store4bf(&vsh[(rg + 16*r)*64 + 4*cg], acc[r]);
    }
    __syncthreads();

    // ---- Phase 8: load out_W; fused attention row (row n, head hq) ----
    load16g(oW + n*64 + c0, &ws[n*LDSW + c0]);

    float g;
    { float gt = gate[hq]; g = 1.f / (1.f + __expf(-gt)); }

    float lg[64];
    #pragma unroll
    for (int k = 0; k < 64; ++k) {
        const uint4* kr = (const uint4*)&ksh[k*64 + c0];
        uint4 a = kr[0], b2 = kr[1];
        u32 wv[8] = {a.x,a.y,a.z,a.w,b2.x,b2.y,b2.z,b2.w};
        float s = 0.f;
        #pragma unroll
        for (int j = 0; j < 8; ++j) {
            s = fmaf(qr[2*j],   bflo(wv[j]), s);
            s = fmaf(qr[2*j+1], bfhi(wv[j]), s);
        }
        lg[k] = s * 0.25f;   // 1/sqrt(dh=16)
    }
    float m = lg[0];
    #pragma unroll
    for (int k = 1; k < 64; ++k) m = fmaxf(m, lg[k]);
    float l = 0.f;
    #pragma unroll
    for (int k = 0; k < 64; ++k) { float e = __expf(lg[k] - m); lg[k] = e; l += e; }

    const float c1 = (1.f - g) / l;
    float oacc[16];
    #pragma unroll
    for (int j = 0; j < 16; ++j) oacc[j] = 0.f;
    float tot = 0.f;
    #pragma unroll
    for (int k = 0; k < 64; ++k) {
        float a = fmaf(c1, lg[k], g * pattn[hq][k]);
        tot += a;
        const uint4* vr = (const uint4*)&vsh[k*64 + c0];
        uint4 va = vr[0], vb = vr[1];
        u32 wv[8] = {va.x,va.y,va.z,va.w,vb.x,vb.y,vb.z,vb.w};
        #pragma unroll
        for (int j = 0; j < 8; ++j) {
            oacc[2*j]   = fmaf(a, bflo(wv[j]), oacc[2*j]);
            oacc[2*j+1] = fmaf(a, bfhi(wv[j]), oacc[2*j+1]);
        }
    }
    const float inv = 1.f / tot;

    #pragma unroll
    for (int j = 0; j < 16; j += 4) {
        float4 cv; cv.x = oacc[j]*inv; cv.y = oacc[j+1]*inv; cv.z = oacc[j+2]*inv; cv.w = oacc[j+3]*inv;
        *(float4*)&xs[n*LDSW + c0 + j] = cv;
    }
    __syncthreads();

    // ---- Phase 9: out = ctx @ out_W + out_b (4x4 scheme), store fp32 ----
    {
        float acc[4][4];
        #pragma unroll
        for (int r = 0; r < 4; ++r)
            #pragma unroll
            for (int c = 0; c < 4; ++c) acc[r][c] = ob[4*cg + c];
        mm4x4(xs, &ws[4*cg], rg, acc);
        #pragma unroll
        for (int r = 0; r < 4; ++r) {
            float4 o; o.x = acc[r][0]; o.y = acc[r][1]; o.z = acc[r][2]; o.w = acc[r][3];
            *(float4*)(out + ((size_t)b*64 + rg + 16*r)*64 + 4*cg) = o;
        }
    }
}

extern "C" void kernel_launch(void* const* d_in, const int* in_sizes, int n_in,
                              void* d_out, int out_size, void* d_ws, size_t ws_size,
                              hipStream_t stream) {
    const int B = in_sizes[0] / (64 * 64);  // 2048
    attn_fused_kernel<<<B, 256, 0, stream>>>(
        (const float*)d_in[0],  (const float*)d_in[1],  (const float*)d_in[2],  (const int*)d_in[3],
        (const float*)d_in[4],  (const float*)d_in[5],  (const float*)d_in[6],  (const float*)d_in[7],
        (const float*)d_in[8],  (const float*)d_in[9],  (const float*)d_in[10], (const float*)d_in[11],
        (const float*)d_in[12], (const float*)d_in[13], (const float*)d_in[14], (const float*)d_in[15],
        (const float*)d_in[16], (const float*)d_in[17], (float*)d_out);
}

// Round 5
// 266.055 us; speedup vs baseline: 1.0935x; 1.0935x over previous
//
#include <hip/hip_runtime.h>

typedef unsigned short u16;
typedef unsigned int u32;

#define LDSW 68  // padded fp32 row stride for xs/ws

__device__ __forceinline__ float bflo(u32 v){ union{float f;u32 i;}c; c.i = v<<16; return c.f; }
__device__ __forceinline__ float bfhi(u32 v){ union{float f;u32 i;}c; c.i = v & 0xFFFF0000u; return c.f; }
__device__ __forceinline__ u16 f2bf(float f){
    union{float f;u32 i;}c; c.f = f;
    u32 i = c.i;
    return (u16)((i + 0x7FFFu + ((i>>16)&1u)) >> 16);  // RNE
}

__device__ __forceinline__ void load16g(const float* __restrict__ g, float* __restrict__ dst){
    const float4* p = (const float4*)g;
    float4 a = p[0], b = p[1], c = p[2], d = p[3];
    *(float4*)&dst[0]  = a;
    *(float4*)&dst[4]  = b;
    *(float4*)&dst[8]  = c;
    *(float4*)&dst[12] = d;
}

// 1-row x 16-col scheme (q only; result stays in registers)
__device__ __forceinline__ void mm_row16(const float* __restrict__ xrow,
                                         const float* __restrict__ wc,
                                         float* __restrict__ acc){
    #pragma unroll
    for (int d = 0; d < 64; d += 4) {
        float4 xv = *(const float4*)&xrow[d];
        float xf[4] = {xv.x, xv.y, xv.z, xv.w};
        #pragma unroll
        for (int dd = 0; dd < 4; ++dd) {
            const float* wr = wc + (d+dd)*LDSW;
            #pragma unroll
            for (int j = 0; j < 16; j += 4) {
                float4 wv = *(const float4*)&wr[j];
                acc[j+0] = fmaf(xf[dd], wv.x, acc[j+0]);
                acc[j+1] = fmaf(xf[dd], wv.y, acc[j+1]);
                acc[j+2] = fmaf(xf[dd], wv.z, acc[j+2]);
                acc[j+3] = fmaf(xf[dd], wv.w, acc[j+3]);
            }
        }
    }
}

// 4-row x 4-col scheme: thread (rg,cg) computes rows {rg,rg+16,rg+32,rg+48},
// cols 4cg..4cg+3. W reads amortize over 4 rows: 128 b128 total per call.
__device__ __forceinline__ void mm4x4(const float* __restrict__ xbase,
                                      const float* __restrict__ wcol,  // &ws[4*cg]
                                      int rg, float acc[4][4]){
    #pragma unroll
    for (int k = 0; k < 64; k += 4) {
        float w_[4][4];
        #pragma unroll
        for (int kk = 0; kk < 4; ++kk) {
            float4 wv = *(const float4*)&wcol[(k+kk)*LDSW];
            w_[kk][0]=wv.x; w_[kk][1]=wv.y; w_[kk][2]=wv.z; w_[kk][3]=wv.w;
        }
        #pragma unroll
        for (int r = 0; r < 4; ++r) {
            float4 xv = *(const float4*)&xbase[(rg + 16*r)*LDSW + k];
            float xf[4] = {xv.x, xv.y, xv.z, xv.w};
            #pragma unroll
            for (int kk = 0; kk < 4; ++kk) {
                #pragma unroll
                for (int c = 0; c < 4; ++c)
                    acc[r][c] = fmaf(xf[kk], w_[kk][c], acc[r][c]);
            }
        }
    }
}

__device__ __forceinline__ void store4bf(u16* __restrict__ dst, const float a[4]){
    uint2 v;
    v.x = (u32)f2bf(a[0]) | ((u32)f2bf(a[1]) << 16);
    v.y = (u32)f2bf(a[2]) | ((u32)f2bf(a[3]) << 16);
    *(uint2*)dst = v;
}

__global__ __launch_bounds__(256, 2) void attn_fused_kernel(
    const float* __restrict__ x, const float* __restrict__ pos, const float* __restrict__ strength,
    const int* __restrict__ embed_id,
    const float* __restrict__ Wq, const float* __restrict__ Wk,
    const float* __restrict__ pW1, const float* __restrict__ pb1,
    const float* __restrict__ pW2, const float* __restrict__ pb2,
    const float* __restrict__ hW, const float* __restrict__ hb,
    const float* __restrict__ gate, const float* __restrict__ embeds,
    const float* __restrict__ oW, const float* __restrict__ ob,
    const float* __restrict__ sW, const float* __restrict__ sb,
    float* __restrict__ out)
{
    // LDS: 17408+17408+8192+8192+1024+1024(union)+256 = 53504 B -> alloc 53760 -> 3 blocks/CU
    __shared__ __align__(16) float xs[64*LDSW];   // x fp32; reused as context
    __shared__ __align__(16) float ws[64*LDSW];   // weight buffer (Wq -> Wk -> E^T -> out_W)
    __shared__ __align__(16) u16  ksh[64*64];     // k bf16, stride 64
    __shared__ __align__(16) u16  vsh[64*64];     // v bf16, stride 64
    __shared__ __align__(16) float t_lds[4][64];
    __shared__ __align__(16) union SPU { float sp[4][64]; float pattn[4][64]; } spu;  // sp dead after ph2; pattn written ph3
    __shared__ __align__(16) float s64[64];

    const int t  = threadIdx.x;
    const int b  = blockIdx.x;
    const int n  = t >> 2;       // attention row 0..63
    const int hq = t & 3;        // head / col-quarter
    const int c0 = hq << 4;      // column base (attention scheme)
    const int cg = t & 15;       // 4x4 scheme: col group (cols 4cg..4cg+3)
    const int rg = t >> 4;       // 4x4 scheme: rows {rg, rg+16, rg+32, rg+48}

    // ---- Phase 1: stage x, strength partials, pos MLP ----
    load16g(x + ((size_t)b*64 + n)*64 + c0, &xs[n*LDSW + c0]);

    {   // s64[d] = strength @ str_W[:,d]; 4 partial slices of 128
        const int d = t & 63, part = t >> 6;
        const float* w = sW + part*128*64 + d;
        const float* s = strength + part*128;
        float acc = 0.f;
        #pragma unroll 8
        for (int i = 0; i < 128; ++i) acc = fmaf(s[i], w[i*64], acc);
        spu.sp[part][d] = acc;
    }

    if (t < 64) {  // pos MLP: p = relu(pos@W1+b1)@W2+b2 ; t[n,h] = p . head_W[:,h]
        float pv[4], h1[4], p8[8];
        const float* gp = pos + ((size_t)b*64 + t)*4;
        #pragma unroll
        for (int i = 0; i < 4; ++i) pv[i] = gp[i];
        #pragma unroll
        for (int j = 0; j < 4; ++j){
            float a = pb1[j];
            #pragma unroll
            for (int i = 0; i < 4; ++i) a = fmaf(pv[i], pW1[i*4+j], a);
            h1[j] = fmaxf(a, 0.f);
        }
        #pragma unroll
        for (int f = 0; f < 8; ++f){
            float a = pb2[f];
            #pragma unroll
            for (int j = 0; j < 4; ++j) a = fmaf(h1[j], pW2[j*8+f], a);
            p8[f] = a;
        }
        #pragma unroll
        for (int h = 0; h < 4; ++h){
            float a = 0.f;
            #pragma unroll
            for (int f = 0; f < 8; ++f) a = fmaf(p8[f], hW[f*4+h], a);
            t_lds[h][t] = a;
        }
    }
    __syncthreads();

    // ---- Phase 2: s64 reduce (last read of sp); load Wq ----
    if (t < 64) s64[t] = spu.sp[0][t] + spu.sp[1][t] + spu.sp[2][t] + spu.sp[3][t] + sb[t];
    load16g(Wq + n*64 + c0, &ws[n*LDSW + c0]);
    __syncthreads();

    // ---- Phase 3: q = x @ Wq (regs); pos_attn softmax -> pattn (overwrites sp space) ----
    {
        const int h = t >> 6, k = t & 63;   // wave h handles head h, lane = k
        float v0 = -t_lds[h][k];
        float m = v0;
        #pragma unroll
        for (int off = 32; off; off >>= 1) m = fmaxf(m, __shfl_xor(m, off));
        float e = __expf(v0 - m);
        float ssum = e;
        #pragma unroll
        for (int off = 32; off; off >>= 1) ssum += __shfl_xor(ssum, off);
        spu.pattn[h][k] = e / ssum;
    }
    float qr[16];
    #pragma unroll
    for (int j = 0; j < 16; ++j) qr[j] = 0.f;
    mm_row16(&xs[n*LDSW], &ws[c0], qr);
    __syncthreads();

    // ---- Phase 4: load Wk ----
    load16g(Wk + n*64 + c0, &ws[n*LDSW + c0]);
    __syncthreads();

    // ---- Phase 5: k = x @ Wk -> ksh bf16 (4x4 scheme) ----
    {
        float acc[4][4];
        #pragma unroll
        for (int r = 0; r < 4; ++r)
            #pragma unroll
            for (int c = 0; c < 4; ++c) acc[r][c] = 0.f;
        mm4x4(xs, &ws[4*cg], rg, acc);
        #pragma unroll
        for (int r = 0; r < 4; ++r)
            store4bf(&ksh[(rg + 16*r)*64 + 4*cg], acc[r]);
    }
    __syncthreads();

    // ---- Phase 6: load E^T (v = x @ E^T) ----
    {
        const float* ge = embeds + (size_t)(*embed_id)*4096 + n*64 + c0;
        float tv[16];
        load16g(ge, tv);
        #pragma unroll
        for (int j = 0; j < 16; ++j) ws[(c0+j)*LDSW + n] = tv[j];
    }
    __syncthreads();

    // ---- Phase 7: v = x @ E^T + s64 -> vsh bf16 (4x4 scheme) ----
    {
        float acc[4][4];
        #pragma unroll
        for (int r = 0; r < 4; ++r)
            #pragma unroll
            for (int c = 0; c < 4; ++c) acc[r][c] = s64[4*cg + c];
        mm4x4(xs, &ws[4*cg], rg, acc);
        #pragma unroll
        for (int r = 0; r < 4; ++r)
            store4bf(&vsh[(rg + 16*r)*64 + 4*cg], acc[r]);
    }
    __syncthreads();

    // ---- Phase 8: load out_W; fused attention row (row n, head hq) ----
    load16g(oW + n*64 + c0, &ws[n*LDSW + c0]);

    float g;
    { float gt = gate[hq]; g = 1.f / (1.f + __expf(-gt)); }

    float lg[64];
    #pragma unroll
    for (int k = 0; k < 64; ++k) {
        const uint4* kr = (const uint4*)&ksh[k*64 + c0];
        uint4 a = kr[0], b2 = kr[1];
        u32 wv[8] = {a.x,a.y,a.z,a.w,b2.x,b2.y,b2.z,b2.w};
        float s = 0.f;
        #pragma unroll
        for (int j = 0; j < 8; ++j) {
            s = fmaf(qr[2*j],   bflo(wv[j]), s);
            s = fmaf(qr[2*j+1], bfhi(wv[j]), s);
        }
        lg[k] = s * 0.25f;   // 1/sqrt(dh=16)
    }
    float m = lg[0];
    #pragma unroll
    for (int k = 1; k < 64; ++k) m = fmaxf(m, lg[k]);
    float l = 0.f;
    #pragma unroll
    for (int k = 0; k < 64; ++k) { float e = __expf(lg[k] - m); lg[k] = e; l += e; }

    const float c1 = (1.f - g) / l;
    float oacc[16];
    #pragma unroll
    for (int j = 0; j < 16; ++j) oacc[j] = 0.f;
    float tot = 0.f;
    #pragma unroll
    for (int k = 0; k < 64; ++k) {
        float a = fmaf(c1, lg[k], g * spu.pattn[hq][k]);
        tot += a;
        const uint4* vr = (const uint4*)&vsh[k*64 + c0];
        uint4 va = vr[0], vb = vr[1];
        u32 wv[8] = {va.x,va.y,va.z,va.w,vb.x,vb.y,vb.z,vb.w};
        #pragma unroll
        for (int j = 0; j < 8; ++j) {
            oacc[2*j]   = fmaf(a, bflo(wv[j]), oacc[2*j]);
            oacc[2*j+1] = fmaf(a, bfhi(wv[j]), oacc[2*j+1]);
        }
    }
    const float inv = 1.f / tot;

    #pragma unroll
    for (int j = 0; j < 16; j += 4) {
        float4 cv; cv.x = oacc[j]*inv; cv.y = oacc[j+1]*inv; cv.z = oacc[j+2]*inv; cv.w = oacc[j+3]*inv;
        *(float4*)&xs[n*LDSW + c0 + j] = cv;
    }
    __syncthreads();

    // ---- Phase 9: out = ctx @ out_W + out_b (4x4 scheme), store fp32 ----
    {
        float acc[4][4];
        #pragma unroll
        for (int r = 0; r < 4; ++r)
            #pragma unroll
            for (int c = 0; c < 4; ++c) acc[r][c] = ob[4*cg + c];
        mm4x4(xs, &ws[4*cg], rg, acc);
        #pragma unroll
        for (int r = 0; r < 4; ++r) {
            float4 o; o.x = acc[r][0]; o.y = acc[r][1]; o.z = acc[r][2]; o.w = acc[r][3];
            *(float4*)(out + ((size_t)b*64 + rg + 16*r)*64 + 4*cg) = o;
        }
    }
}

extern "C" void kernel_launch(void* const* d_in, const int* in_sizes, int n_in,
                              void* d_out, int out_size, void* d_ws, size_t ws_size,
                              hipStream_t stream) {
    const int B = in_sizes[0] / (64 * 64);  // 2048
    attn_fused_kernel<<<B, 256, 0, stream>>>(
        (const float*)d_in[0],  (const float*)d_in[1],  (const float*)d_in[2],  (const int*)d_in[3],
        (const float*)d_in[4],  (const float*)d_in[5],  (const float*)d_in[6],  (const float*)d_in[7],
        (const float*)d_in[8],  (const float*)d_in[9],  (const float*)d_in[10], (const float*)d_in[11],
        (const float*)d_in[12], (const float*)d_in[13], (const float*)d_in[14], (const float*)d_in[15],
        (const float*)d_in[16], (const float*)d_in[17], (float*)d_out);
}

// Round 6
// 149.125 us; speedup vs baseline: 1.9509x; 1.7841x over previous
//
#include <hip/hip_runtime.h>

typedef unsigned short u16;
typedef unsigned int u32;
typedef short bf8 __attribute__((ext_vector_type(8)));   // 8 bf16 = 4 VGPR (MFMA A/B frag)
typedef float f4v __attribute__((ext_vector_type(4)));   // 16x16 C/D frag
typedef float f16v __attribute__((ext_vector_type(16))); // 32x32 C/D frag

#define STR 72   // bf16 row stride (144 B): rotates banks, 16B-aligned frag reads

__device__ __forceinline__ u32 f2bf(float f){
    union{float f;u32 i;}c; c.f=f; u32 i=c.i;
    return (i + 0x7FFFu + ((i>>16)&1u)) >> 16;  // RNE
}

// stage 16 fp32 (row n, cols c0..c0+15) -> bf16 LDS row-major
__device__ __forceinline__ void stage_row16(const float* __restrict__ g, short* __restrict__ dst,
                                            int n, int c0){
    const float4* p = (const float4*)(g + n*64 + c0);
    float4 a=p[0], b=p[1], c=p[2], d=p[3];
    uint4 o0, o1;
    o0.x = f2bf(a.x)|(f2bf(a.y)<<16); o0.y = f2bf(a.z)|(f2bf(a.w)<<16);
    o0.z = f2bf(b.x)|(f2bf(b.y)<<16); o0.w = f2bf(b.z)|(f2bf(b.w)<<16);
    o1.x = f2bf(c.x)|(f2bf(c.y)<<16); o1.y = f2bf(c.z)|(f2bf(c.w)<<16);
    o1.z = f2bf(d.x)|(f2bf(d.y)<<16); o1.w = f2bf(d.z)|(f2bf(d.w)<<16);
    *(uint4*)&dst[n*STR + c0]     = o0;
    *(uint4*)&dst[n*STR + c0 + 8] = o1;
}

// stage W[64 in][64 out] fp32 -> Wt[out][in] bf16 (B-operand wants B^T row-major)
__device__ __forceinline__ void stage_wt(const float* __restrict__ W, short* __restrict__ dst, int t){
    const int kp = t >> 3, ng = t & 7;            // k-pair 0..31, n-group 0..7
    const float4* r0 = (const float4*)(W + (2*kp  )*64 + 8*ng);
    const float4* r1 = (const float4*)(W + (2*kp+1)*64 + 8*ng);
    float4 a0=r0[0], a1=r0[1], b0=r1[0], b1=r1[1];
    float lo[8]={a0.x,a0.y,a0.z,a0.w,a1.x,a1.y,a1.z,a1.w};
    float hi[8]={b0.x,b0.y,b0.z,b0.w,b1.x,b1.y,b1.z,b1.w};
    #pragma unroll
    for (int i=0;i<8;++i)
        *(u32*)&dst[(8*ng+i)*STR + 2*kp] = f2bf(lo[i]) | (f2bf(hi[i])<<16);
}

// 64x64x64 via 16x16x32: wave w owns rows 16w..16w+15, all 4 col-tiles
__device__ __forceinline__ void mmlin(const short* __restrict__ X, const short* __restrict__ Wt,
                                      int w, int l15, int quad, f4v c[4]){
    bf8 a0 = *(const bf8*)&X[(16*w + l15)*STR + quad*8];
    bf8 a1 = *(const bf8*)&X[(16*w + l15)*STR + 32 + quad*8];
    #pragma unroll
    for (int nt=0; nt<4; ++nt){
        bf8 b0 = *(const bf8*)&Wt[(16*nt + l15)*STR + quad*8];
        bf8 b1 = *(const bf8*)&Wt[(16*nt + l15)*STR + 32 + quad*8];
        c[nt] = __builtin_amdgcn_mfma_f32_16x16x32_bf16(a0, b0, c[nt], 0,0,0);
        c[nt] = __builtin_amdgcn_mfma_f32_16x16x32_bf16(a1, b1, c[nt], 0,0,0);
    }
}

__global__ __launch_bounds__(256, 2) void attn_mfma_kernel(
    const float* __restrict__ x, const float* __restrict__ pos, const float* __restrict__ strength,
    const int* __restrict__ embed_id,
    const float* __restrict__ Wq, const float* __restrict__ Wk,
    const float* __restrict__ pW1, const float* __restrict__ pb1,
    const float* __restrict__ pW2, const float* __restrict__ pb2,
    const float* __restrict__ hW, const float* __restrict__ hb,
    const float* __restrict__ gate, const float* __restrict__ embeds,
    const float* __restrict__ oW, const float* __restrict__ ob,
    const float* __restrict__ sW, const float* __restrict__ sb,
    float* __restrict__ out)
{
    // 5 x 9216B bf16 buffers + small fp32: 48384 B total
    __shared__ short B0[64*STR];  // xbf -> P(head0)
    __shared__ short B1[64*STR];  // WqT -> E -> P(head1) -> oWT
    __shared__ short B2[64*STR];  // qbf -> P(head2)
    __shared__ short B3[64*STR];  // kbf -> P(head3) -> ctx
    __shared__ short VT[64*STR];  // WkT -> V^T
    __shared__ float t_lds[4][64];
    __shared__ float sp[4][64];
    __shared__ float s64v[64];

    const int t    = threadIdx.x;
    const int b    = blockIdx.x;
    const int lane = t & 63;
    const int w    = t >> 6;        // wave id = head id
    const int l15  = lane & 15;
    const int l31  = lane & 31;
    const int l5   = lane >> 5;
    const int quad = lane >> 4;
    const int n    = t >> 2;        // staging row
    const int c0   = (t & 3) << 4;  // staging col base

    // ================= P0: stage x, WqT, WkT(->VT); strength partials; pos MLP =================
    stage_row16(x + (size_t)b*4096, B0, n, c0);
    stage_wt(Wq, B1, t);
    stage_wt(Wk, VT, t);

    {   // s64 partials: 4 slices of 128
        const int d = t & 63, part = t >> 6;
        const float* wp = sW + part*128*64 + d;
        const float* s  = strength + part*128;
        float acc = 0.f;
        #pragma unroll 8
        for (int i = 0; i < 128; ++i) acc = fmaf(s[i], wp[i*64], acc);
        sp[part][d] = acc;
    }

    if (t < 64) {  // pos MLP -> t_lds[h][n]
        float pv[4], h1[4], p8[8];
        const float* gp = pos + ((size_t)b*64 + t)*4;
        #pragma unroll
        for (int i = 0; i < 4; ++i) pv[i] = gp[i];
        #pragma unroll
        for (int j = 0; j < 4; ++j){
            float a = pb1[j];
            #pragma unroll
            for (int i = 0; i < 4; ++i) a = fmaf(pv[i], pW1[i*4+j], a);
            h1[j] = fmaxf(a, 0.f);
        }
        #pragma unroll
        for (int f = 0; f < 8; ++f){
            float a = pb2[f];
            #pragma unroll
            for (int j = 0; j < 4; ++j) a = fmaf(h1[j], pW2[j*8+f], a);
            p8[f] = a;
        }
        #pragma unroll
        for (int h = 0; h < 4; ++h){
            float a = 0.f;
            #pragma unroll
            for (int f = 0; f < 8; ++f) a = fmaf(p8[f], hW[f*4+h], a);
            t_lds[h][t] = a;
        }
    }
    __syncthreads();

    // ================= P1: q = x@Wq (MFMA) *0.25 -> B2; s64 reduce =================
    if (t < 64) s64v[t] = sp[0][t] + sp[1][t] + sp[2][t] + sp[3][t] + sb[t];
    {
        f4v c[4];
        #pragma unroll
        for (int nt=0;nt<4;++nt){ c[nt][0]=0.f;c[nt][1]=0.f;c[nt][2]=0.f;c[nt][3]=0.f; }
        mmlin(B0, B1, w, l15, quad, c);
        __syncthreads();   // all frag reads of B0/B1 done before B2 write? B2 untouched; barrier protects B1 for E later & B2 vs S^T ordering
        #pragma unroll
        for (int nt=0;nt<4;++nt)
            #pragma unroll
            for (int r=0;r<4;++r)
                B2[(16*w + quad*4 + r)*STR + 16*nt + l15] = (short)f2bf(0.25f*c[nt][r]);
    }
    __syncthreads();

    // ================= P2: k = x@Wk (B=VT) -> B3; stage E -> B1 =================
    {
        f4v c[4];
        #pragma unroll
        for (int nt=0;nt<4;++nt){ c[nt][0]=0.f;c[nt][1]=0.f;c[nt][2]=0.f;c[nt][3]=0.f; }
        mmlin(B0, VT, w, l15, quad, c);
        stage_row16(embeds + (size_t)(*embed_id)*4096, B1, n, c0);  // B1 free (post-P1 barrier)
        __syncthreads();   // WkT reads done before VT overwritten in P3
        #pragma unroll
        for (int nt=0;nt<4;++nt)
            #pragma unroll
            for (int r=0;r<4;++r)
                B3[(16*w + quad*4 + r)*STR + 16*nt + l15] = (short)f2bf(c[nt][r]);
    }
    __syncthreads();

    // ================= P3: v = x@E^T + s64 -> VT transposed (b64 packs) =================
    {
        f4v c[4];
        #pragma unroll
        for (int nt=0;nt<4;++nt){ c[nt][0]=0.f;c[nt][1]=0.f;c[nt][2]=0.f;c[nt][3]=0.f; }
        mmlin(B0, B1, w, l15, quad, c);   // B = E row-major == (E^T)^T  ✓
        #pragma unroll
        for (int nt=0;nt<4;++nt){
            float sv = s64v[16*nt + l15];
            uint2 pk;
            pk.x = f2bf(c[nt][0]+sv) | (f2bf(c[nt][1]+sv)<<16);
            pk.y = f2bf(c[nt][2]+sv) | (f2bf(c[nt][3]+sv)<<16);
            *(uint2*)&VT[(16*nt + l15)*STR + 16*w + quad*4] = pk;   // VT[d][krow]
        }
    }
    __syncthreads();

    // ================= P4: S^T = K@Q^T (32x32x16, K=16=dh); softmax+mix in C/D layout =================
    float g = 1.f/(1.f + __expf(-gate[w]));
    f16v S[2][2];
    {
        bf8 ka0 = *(const bf8*)&B3[(     l31)*STR + 16*w + 8*l5];
        bf8 ka1 = *(const bf8*)&B3[(32 + l31)*STR + 16*w + 8*l5];
        bf8 qb0 = *(const bf8*)&B2[(     l31)*STR + 16*w + 8*l5];
        bf8 qb1 = *(const bf8*)&B2[(32 + l31)*STR + 16*w + 8*l5];
        #pragma unroll
        for (int mt=0;mt<2;++mt)
            #pragma unroll
            for (int nt=0;nt<2;++nt)
                #pragma unroll
                for (int i=0;i<16;++i) S[mt][nt][i] = 0.f;
        S[0][0] = __builtin_amdgcn_mfma_f32_32x32x16_bf16(ka0, qb0, S[0][0], 0,0,0);
        S[0][1] = __builtin_amdgcn_mfma_f32_32x32x16_bf16(ka0, qb1, S[0][1], 0,0,0);
        S[1][0] = __builtin_amdgcn_mfma_f32_32x32x16_bf16(ka1, qb0, S[1][0], 0,0,0);
        S[1][1] = __builtin_amdgcn_mfma_f32_32x32x16_bf16(ka1, qb1, S[1][1], 0,0,0);
    }
    // pos-attn (q-independent): lane's 32 k-values match C/D rows: k = 32mt+8rg2+4l5+(reg&3)
    float ep[32];
    {
        #pragma unroll
        for (int mt=0;mt<2;++mt)
            #pragma unroll
            for (int rg=0;rg<4;++rg){
                float4 tv = *(const float4*)&t_lds[w][32*mt + 8*rg + 4*l5];
                ep[mt*16+rg*4+0] = -tv.x; ep[mt*16+rg*4+1] = -tv.y;
                ep[mt*16+rg*4+2] = -tv.z; ep[mt*16+rg*4+3] = -tv.w;
            }
        float mx = ep[0];
        #pragma unroll
        for (int i=1;i<32;++i) mx = fmaxf(mx, ep[i]);
        mx = fmaxf(mx, __shfl_xor(mx, 32));
        float sm = 0.f;
        #pragma unroll
        for (int i=0;i<32;++i){ ep[i] = __expf(ep[i]-mx); sm += ep[i]; }
        sm += __shfl_xor(sm, 32);
        float gi = g / sm;
        #pragma unroll
        for (int i=0;i<32;++i) ep[i] *= gi;   // = g * pattn[k]
    }
    float inv[2];
    #pragma unroll
    for (int nt=0;nt<2;++nt){   // two q columns per lane
        float m = S[0][nt][0];
        #pragma unroll
        for (int i=1;i<16;++i) m = fmaxf(m, S[0][nt][i]);
        #pragma unroll
        for (int i=0;i<16;++i) m = fmaxf(m, S[1][nt][i]);
        m = fmaxf(m, __shfl_xor(m, 32));
        float l = 0.f;
        #pragma unroll
        for (int mt=0;mt<2;++mt)
            #pragma unroll
            for (int i=0;i<16;++i){ float e = __expf(S[mt][nt][i]-m); S[mt][nt][i] = e; l += e; }
        l += __shfl_xor(l, 32);
        float c1 = (1.f - g) / l;
        float tot = 0.f;
        #pragma unroll
        for (int mt=0;mt<2;++mt)
            #pragma unroll
            for (int i=0;i<16;++i){ float a = fmaf(c1, S[mt][nt][i], ep[mt*16+i]); S[mt][nt][i] = a; tot += a; }
        tot += __shfl_xor(tot, 32);
        inv[nt] = 1.f / tot;
    }
    __syncthreads();   // all S^T frag reads of B2/B3 complete before P overwrites

    // ================= P5: P writeback row-major to per-head buffer (b64 packs) =================
    short* Pb = (w==0) ? B0 : (w==1) ? B1 : (w==2) ? B2 : B3;
    #pragma unroll
    for (int nt=0;nt<2;++nt)
        #pragma unroll
        for (int mt=0;mt<2;++mt)
            #pragma unroll
            for (int rg=0;rg<4;++rg){
                float v0 = S[mt][nt][rg*4+0]*inv[nt], v1 = S[mt][nt][rg*4+1]*inv[nt];
                float v2 = S[mt][nt][rg*4+2]*inv[nt], v3 = S[mt][nt][rg*4+3]*inv[nt];
                uint2 pk;
                pk.x = f2bf(v0) | (f2bf(v1)<<16);
                pk.y = f2bf(v2) | (f2bf(v3)<<16);
                *(uint2*)&Pb[(32*nt + l31)*STR + 32*mt + 8*rg + 4*l5] = pk;
            }
    // no barrier: PV reads only this wave's own Pb (same-wave lgkmcnt ordering)

    // ================= P6: O_h = P_h @ V_h (16x16x32) =================
    f4v o[4];
    {
        bf8 bv0 = *(const bf8*)&VT[(16*w + l15)*STR + quad*8];
        bf8 bv1 = *(const bf8*)&VT[(16*w + l15)*STR + 32 + quad*8];
        #pragma unroll
        for (int mt=0;mt<4;++mt){
            o[mt][0]=0.f;o[mt][1]=0.f;o[mt][2]=0.f;o[mt][3]=0.f;
            bf8 a0 = *(const bf8*)&Pb[(16*mt + l15)*STR + quad*8];
            bf8 a1 = *(const bf8*)&Pb[(16*mt + l15)*STR + 32 + quad*8];
            o[mt] = __builtin_amdgcn_mfma_f32_16x16x32_bf16(a0, bv0, o[mt], 0,0,0);
            o[mt] = __builtin_amdgcn_mfma_f32_16x16x32_bf16(a1, bv1, o[mt], 0,0,0);
        }
    }
    __syncthreads();   // all P reads done before ctx/oWT overwrite B3/B1

    // ================= P7: ctx -> B3 row-major; stage oWT -> B1 =================
    #pragma unroll
    for (int mt=0;mt<4;++mt)
        #pragma unroll
        for (int r=0;r<4;++r)
            B3[(16*mt + quad*4 + r)*STR + 16*w + l15] = (short)f2bf(o[mt][r]);
    stage_wt(oW, B1, t);
    __syncthreads();

    // ================= P8: out = ctx@oW + ob (MFMA) -> global =================
    {
        f4v c[4];
        #pragma unroll
        for (int nt=0;nt<4;++nt){
            float obv = ob[16*nt + l15];
            c[nt][0]=obv;c[nt][1]=obv;c[nt][2]=obv;c[nt][3]=obv;
        }
        mmlin(B3, B1, w, l15, quad, c);
        #pragma unroll
        for (int nt=0;nt<4;++nt)
            #pragma unroll
            for (int r=0;r<4;++r)
                out[((size_t)b*64 + 16*w + quad*4 + r)*64 + 16*nt + l15] = c[nt][r];
    }
}

extern "C" void kernel_launch(void* const* d_in, const int* in_sizes, int n_in,
                              void* d_out, int out_size, void* d_ws, size_t ws_size,
                              hipStream_t stream) {
    const int B = in_sizes[0] / (64 * 64);  // 2048
    attn_mfma_kernel<<<B, 256, 0, stream>>>(
        (const float*)d_in[0],  (const float*)d_in[1],  (const float*)d_in[2],  (const int*)d_in[3],
        (const float*)d_in[4],  (const float*)d_in[5],  (const float*)d_in[6],  (const float*)d_in[7],
        (const float*)d_in[8],  (const float*)d_in[9],  (const float*)d_in[10], (const float*)d_in[11],
        (const float*)d_in[12], (const float*)d_in[13], (const float*)d_in[14], (const float*)d_in[15],
        (const float*)d_in[16], (const float*)d_in[17], (float*)d_out);
}

// Round 7
// 140.382 us; speedup vs baseline: 2.0724x; 1.0623x over previous
//
#include <hip/hip_runtime.h>

typedef unsigned short u16;
typedef unsigned int u32;
typedef short bf8 __attribute__((ext_vector_type(8)));   // 8 bf16 = 4 VGPR (MFMA A/B frag)
typedef float f4v __attribute__((ext_vector_type(4)));   // 16x16 C/D frag
typedef float f16v __attribute__((ext_vector_type(16))); // 32x32 C/D frag

#define STR 72   // bf16 LDS row stride (144 B): 16B-aligned rows, 2-way (free) bank pattern

__device__ __forceinline__ u32 f2bf(float f){
    union{float f;u32 i;}c; c.f=f; u32 i=c.i;
    return (i + 0x7FFFu + ((i>>16)&1u)) >> 16;  // RNE
}

// stage 16 fp32 (row n, cols c0..c0+15) -> bf16 LDS row-major
__device__ __forceinline__ void stage_row16(const float* __restrict__ g, short* __restrict__ dst,
                                            int n, int c0){
    const float4* p = (const float4*)(g + n*64 + c0);
    float4 a=p[0], b=p[1], c=p[2], d=p[3];
    uint4 o0, o1;
    o0.x = f2bf(a.x)|(f2bf(a.y)<<16); o0.y = f2bf(a.z)|(f2bf(a.w)<<16);
    o0.z = f2bf(b.x)|(f2bf(b.y)<<16); o0.w = f2bf(b.z)|(f2bf(b.w)<<16);
    o1.x = f2bf(c.x)|(f2bf(c.y)<<16); o1.y = f2bf(c.z)|(f2bf(c.w)<<16);
    o1.z = f2bf(d.x)|(f2bf(d.y)<<16); o1.w = f2bf(d.z)|(f2bf(d.w)<<16);
    *(uint4*)&dst[n*STR + c0]     = o0;
    *(uint4*)&dst[n*STR + c0 + 8] = o1;
}

// copy pre-converted bf16 64x64 (stride 64) from global -> LDS (stride STR)
__device__ __forceinline__ void copy8k(const u16* __restrict__ src, short* __restrict__ dst, int t){
    const int r = t >> 2, cs = (t & 3) << 4;
    const uint4* s = (const uint4*)(src + r*64 + cs);
    uint4 a = s[0], b = s[1];
    *(uint4*)&dst[r*STR + cs]     = a;
    *(uint4*)&dst[r*STR + cs + 8] = b;
}

// 64x64x64 via 16x16x32: wave w owns rows 16w..16w+15, all 4 col-tiles
__device__ __forceinline__ void mmlin(const short* __restrict__ X, const short* __restrict__ Wt,
                                      int w, int l15, int quad, f4v c[4]){
    bf8 a0 = *(const bf8*)&X[(16*w + l15)*STR + quad*8];
    bf8 a1 = *(const bf8*)&X[(16*w + l15)*STR + 32 + quad*8];
    #pragma unroll
    for (int nt=0; nt<4; ++nt){
        bf8 b0 = *(const bf8*)&Wt[(16*nt + l15)*STR + quad*8];
        bf8 b1 = *(const bf8*)&Wt[(16*nt + l15)*STR + 32 + quad*8];
        c[nt] = __builtin_amdgcn_mfma_f32_16x16x32_bf16(a0, b0, c[nt], 0,0,0);
        c[nt] = __builtin_amdgcn_mfma_f32_16x16x32_bf16(a1, b1, c[nt], 0,0,0);
    }
}

// ================= precompute kernel: batch-invariant prep + per-(b,h) pos softmax =================
__global__ __launch_bounds__(256) void pre_kernel(
    const float* __restrict__ pos, const float* __restrict__ strength,
    const int* __restrict__ embed_id,
    const float* __restrict__ Wq, const float* __restrict__ Wk,
    const float* __restrict__ pW1, const float* __restrict__ pb1,
    const float* __restrict__ pW2, const float* __restrict__ pb2,
    const float* __restrict__ hW, const float* __restrict__ embeds,
    const float* __restrict__ oW, const float* __restrict__ sW,
    const float* __restrict__ sb,
    float* __restrict__ ws_s64, float* __restrict__ ws_pat,
    u16* __restrict__ ws_wq, u16* __restrict__ ws_wk,
    u16* __restrict__ ws_ow, u16* __restrict__ ws_e, int B)
{
    const int blk = blockIdx.x;
    const int t = threadIdx.x;

    if (blk < B) {
        // per-batch: pos MLP -> t[h][n]; softmax_k(-t) -> ws_pat[b][h][k]
        __shared__ float t_l[4][64];
        if (t < 64) {
            float pv[4], h1[4], p8[8];
            const float* gp = pos + ((size_t)blk*64 + t)*4;
            #pragma unroll
            for (int i = 0; i < 4; ++i) pv[i] = gp[i];
            #pragma unroll
            for (int j = 0; j < 4; ++j){
                float a = pb1[j];
                #pragma unroll
                for (int i = 0; i < 4; ++i) a = fmaf(pv[i], pW1[i*4+j], a);
                h1[j] = fmaxf(a, 0.f);
            }
            #pragma unroll
            for (int f = 0; f < 8; ++f){
                float a = pb2[f];
                #pragma unroll
                for (int j = 0; j < 4; ++j) a = fmaf(h1[j], pW2[j*8+f], a);
                p8[f] = a;
            }
            #pragma unroll
            for (int h = 0; h < 4; ++h){
                float a = 0.f;
                #pragma unroll
                for (int f = 0; f < 8; ++f) a = fmaf(p8[f], hW[f*4+h], a);
                t_l[h][t] = a;
            }
        }
        __syncthreads();
        const int h = t >> 6, k = t & 63;
        float v0 = -t_l[h][k];
        float m = v0;
        #pragma unroll
        for (int off = 32; off; off >>= 1) m = fmaxf(m, __shfl_xor(m, off));
        float e = __expf(v0 - m);
        float ssum = e;
        #pragma unroll
        for (int off = 32; off; off >>= 1) ssum += __shfl_xor(ssum, off);
        ws_pat[((size_t)blk*4 + h)*64 + k] = e / ssum;
        return;
    }

    const int j = blk - B;
    if (j < 3) {
        // transpose W[64 in][64 out] fp32 -> bf16 [out][in], stride 64
        const float* W = (j==0) ? Wq : (j==1) ? Wk : oW;
        u16* dst = (j==0) ? ws_wq : (j==1) ? ws_wk : ws_ow;
        const int kp = t >> 3, ng = t & 7;
        const float4* r0 = (const float4*)(W + (2*kp  )*64 + 8*ng);
        const float4* r1 = (const float4*)(W + (2*kp+1)*64 + 8*ng);
        float4 a0=r0[0], a1=r0[1], b0=r1[0], b1=r1[1];
        float lo[8]={a0.x,a0.y,a0.z,a0.w,a1.x,a1.y,a1.z,a1.w};
        float hi[8]={b0.x,b0.y,b0.z,b0.w,b1.x,b1.y,b1.z,b1.w};
        #pragma unroll
        for (int i=0;i<8;++i)
            *(u32*)&dst[(8*ng+i)*64 + 2*kp] = f2bf(lo[i]) | (f2bf(hi[i])<<16);
    } else {
        // E = embeds[id] -> bf16 row-major; s64 = strength @ str_W + str_b
        __shared__ float sp[4][64];
        {
            const int n = t >> 2, c0 = (t & 3) << 4;
            const float4* p = (const float4*)(embeds + (size_t)(*embed_id)*4096 + n*64 + c0);
            float4 a=p[0], b=p[1], c=p[2], d=p[3];
            uint4 o0, o1;
            o0.x = f2bf(a.x)|(f2bf(a.y)<<16); o0.y = f2bf(a.z)|(f2bf(a.w)<<16);
            o0.z = f2bf(b.x)|(f2bf(b.y)<<16); o0.w = f2bf(b.z)|(f2bf(b.w)<<16);
            o1.x = f2bf(c.x)|(f2bf(c.y)<<16); o1.y = f2bf(c.z)|(f2bf(c.w)<<16);
            o1.z = f2bf(d.x)|(f2bf(d.y)<<16); o1.w = f2bf(d.z)|(f2bf(d.w)<<16);
            *(uint4*)&ws_e[n*64 + c0]     = o0;
            *(uint4*)&ws_e[n*64 + c0 + 8] = o1;
        }
        {
            const int d = t & 63, part = t >> 6;
            const float* wp = sW + part*128*64 + d;
            const float* s  = strength + part*128;
            float acc = 0.f;
            #pragma unroll 8
            for (int i = 0; i < 128; ++i) acc = fmaf(s[i], wp[i*64], acc);
            sp[part][d] = acc;
        }
        __syncthreads();
        if (t < 64) ws_s64[t] = sp[0][t] + sp[1][t] + sp[2][t] + sp[3][t] + sb[t];
    }
}

// ================= main kernel =================
__global__ __launch_bounds__(256, 2) void attn_main_kernel(
    const float* __restrict__ x, const float* __restrict__ gate, const float* __restrict__ ob,
    const float* __restrict__ ws_s64, const float* __restrict__ ws_pat,
    const u16* __restrict__ ws_wq, const u16* __restrict__ ws_wk,
    const u16* __restrict__ ws_ow, const u16* __restrict__ ws_e,
    float* __restrict__ out)
{
    // 6 x 9216 B = 55296 B -> 2 blocks/CU
    __shared__ short B0[64*STR];  // xbf -> P(head0)
    __shared__ short B1[64*STR];  // WqT -> E -> oWT
    __shared__ short B2[64*STR];  // qbf -> P(head2)
    __shared__ short B3[64*STR];  // kbf -> P(head3) -> ctx
    __shared__ short VT[64*STR];  // WkT -> V^T
    __shared__ short PX[64*STR];  // P(head1)

    const int t    = threadIdx.x;
    const int b    = blockIdx.x;
    const int lane = t & 63;
    const int w    = t >> 6;        // wave id = head id
    const int l15  = lane & 15;
    const int l31  = lane & 31;
    const int l5   = lane >> 5;
    const int quad = lane >> 4;
    const int n    = t >> 2;        // staging row
    const int c0   = (t & 3) << 4;  // staging col base

    // ---- P0: stage x(convert), WqT->B1, WkT->VT; early-load E, oWT, s64, gate ----
    stage_row16(x + (size_t)b*4096, B0, n, c0);
    copy8k(ws_wq, B1, t);
    copy8k(ws_wk, VT, t);

    uint4 eA, eB, owA, owB;
    {
        const int r = t >> 2, cs = (t & 3) << 4;
        const uint4* se = (const uint4*)(ws_e + r*64 + cs);
        eA = se[0]; eB = se[1];
        const uint4* so = (const uint4*)(ws_ow + r*64 + cs);
        owA = so[0]; owB = so[1];
    }
    float svv[4];
    #pragma unroll
    for (int nt=0;nt<4;++nt) svv[nt] = ws_s64[16*nt + l15];
    float g = 1.f/(1.f + __expf(-gate[w]));
    float obv[4];
    #pragma unroll
    for (int nt=0;nt<4;++nt) obv[nt] = ob[16*nt + l15];
    __syncthreads();

    // ---- P1: q = x@Wq, k = x@Wk (fused); then q->B2 (*0.25), k->B3, E->B1 ----
    {
        f4v cq[4], ck[4];
        #pragma unroll
        for (int nt=0;nt<4;++nt){
            cq[nt][0]=0.f;cq[nt][1]=0.f;cq[nt][2]=0.f;cq[nt][3]=0.f;
            ck[nt][0]=0.f;ck[nt][1]=0.f;ck[nt][2]=0.f;ck[nt][3]=0.f;
        }
        mmlin(B0, B1, w, l15, quad, cq);
        mmlin(B0, VT, w, l15, quad, ck);
        __syncthreads();   // B1/VT frag reads done
        #pragma unroll
        for (int nt=0;nt<4;++nt)
            #pragma unroll
            for (int r=0;r<4;++r){
                B2[(16*w + quad*4 + r)*STR + 16*nt + l15] = (short)f2bf(0.25f*cq[nt][r]);
                B3[(16*w + quad*4 + r)*STR + 16*nt + l15] = (short)f2bf(ck[nt][r]);
            }
        const int r = t >> 2, cs = (t & 3) << 4;
        *(uint4*)&B1[r*STR + cs]     = eA;
        *(uint4*)&B1[r*STR + cs + 8] = eB;
    }
    __syncthreads();

    // ---- P2: v = x@E^T + s64 -> V^T into VT; oWT -> B1 ----
    {
        f4v c[4];
        #pragma unroll
        for (int nt=0;nt<4;++nt){ c[nt][0]=0.f;c[nt][1]=0.f;c[nt][2]=0.f;c[nt][3]=0.f; }
        mmlin(B0, B1, w, l15, quad, c);   // B = E row-major == (E^T)^T
        __syncthreads();   // B1-E and VT-Wk reads done
        #pragma unroll
        for (int nt=0;nt<4;++nt){
            float sv = svv[nt];
            uint2 pk;
            pk.x = f2bf(c[nt][0]+sv) | (f2bf(c[nt][1]+sv)<<16);
            pk.y = f2bf(c[nt][2]+sv) | (f2bf(c[nt][3]+sv)<<16);
            *(uint2*)&VT[(16*nt + l15)*STR + 16*w + quad*4] = pk;   // VT[d][krow]
        }
        const int r = t >> 2, cs = (t & 3) << 4;
        *(uint4*)&B1[r*STR + cs]     = owA;
        *(uint4*)&B1[r*STR + cs + 8] = owB;
    }
    __syncthreads();

    // ---- P4: S^T = K@Q^T (32x32x16); softmax + gate-mix in C/D layout ----
    f16v S[2][2];
    {
        bf8 ka0 = *(const bf8*)&B3[(     l31)*STR + 16*w + 8*l5];
        bf8 ka1 = *(const bf8*)&B3[(32 + l31)*STR + 16*w + 8*l5];
        bf8 qb0 = *(const bf8*)&B2[(     l31)*STR + 16*w + 8*l5];
        bf8 qb1 = *(const bf8*)&B2[(32 + l31)*STR + 16*w + 8*l5];
        #pragma unroll
        for (int mt=0;mt<2;++mt)
            #pragma unroll
            for (int nt=0;nt<2;++nt)
                #pragma unroll
                for (int i=0;i<16;++i) S[mt][nt][i] = 0.f;
        S[0][0] = __builtin_amdgcn_mfma_f32_32x32x16_bf16(ka0, qb0, S[0][0], 0,0,0);
        S[0][1] = __builtin_amdgcn_mfma_f32_32x32x16_bf16(ka0, qb1, S[0][1], 0,0,0);
        S[1][0] = __builtin_amdgcn_mfma_f32_32x32x16_bf16(ka1, qb0, S[1][0], 0,0,0);
        S[1][1] = __builtin_amdgcn_mfma_f32_32x32x16_bf16(ka1, qb1, S[1][1], 0,0,0);
    }
    // g * pattn, loaded in C/D row layout: k = 32mt + 8rg + 4*l5 + j
    float ep[32];
    {
        const float* pp = ws_pat + ((size_t)b*4 + w)*64;
        #pragma unroll
        for (int mt=0;mt<2;++mt)
            #pragma unroll
            for (int rg=0;rg<4;++rg){
                float4 tv = *(const float4*)&pp[32*mt + 8*rg + 4*l5];
                ep[mt*16+rg*4+0] = g*tv.x; ep[mt*16+rg*4+1] = g*tv.y;
                ep[mt*16+rg*4+2] = g*tv.z; ep[mt*16+rg*4+3] = g*tv.w;
            }
    }
    float inv[2];
    #pragma unroll
    for (int nt=0;nt<2;++nt){   // two q columns per lane
        float m = S[0][nt][0];
        #pragma unroll
        for (int i=1;i<16;++i) m = fmaxf(m, S[0][nt][i]);
        #pragma unroll
        for (int i=0;i<16;++i) m = fmaxf(m, S[1][nt][i]);
        m = fmaxf(m, __shfl_xor(m, 32));
        float l = 0.f;
        #pragma unroll
        for (int mt=0;mt<2;++mt)
            #pragma unroll
            for (int i=0;i<16;++i){ float e = __expf(S[mt][nt][i]-m); S[mt][nt][i] = e; l += e; }
        l += __shfl_xor(l, 32);
        float c1 = (1.f - g) / l;
        float tot = 0.f;
        #pragma unroll
        for (int mt=0;mt<2;++mt)
            #pragma unroll
            for (int i=0;i<16;++i){ float a = fmaf(c1, S[mt][nt][i], ep[mt*16+i]); S[mt][nt][i] = a; tot += a; }
        tot += __shfl_xor(tot, 32);
        inv[nt] = 1.f / tot;
    }
    __syncthreads();   // all S^T frag reads of B2/B3 done before P overwrites

    // ---- P5: P writeback row-major to per-head buffer (b64 packs) ----
    short* Pb = (w==0) ? B0 : (w==1) ? PX : (w==2) ? B2 : B3;
    #pragma unroll
    for (int nt=0;nt<2;++nt)
        #pragma unroll
        for (int mt=0;mt<2;++mt)
            #pragma unroll
            for (int rg=0;rg<4;++rg){
                float v0 = S[mt][nt][rg*4+0]*inv[nt], v1 = S[mt][nt][rg*4+1]*inv[nt];
                float v2 = S[mt][nt][rg*4+2]*inv[nt], v3 = S[mt][nt][rg*4+3]*inv[nt];
                uint2 pk;
                pk.x = f2bf(v0) | (f2bf(v1)<<16);
                pk.y = f2bf(v2) | (f2bf(v3)<<16);
                *(uint2*)&Pb[(32*nt + l31)*STR + 32*mt + 8*rg + 4*l5] = pk;
            }
    // no barrier: P6 reads only this wave's own Pb (same-wave LDS ordering)

    // ---- P6: O_h = P_h @ V_h (16x16x32) ----
    f4v o[4];
    {
        bf8 bv0 = *(const bf8*)&VT[(16*w + l15)*STR + quad*8];
        bf8 bv1 = *(const bf8*)&VT[(16*w + l15)*STR + 32 + quad*8];
        #pragma unroll
        for (int mt=0;mt<4;++mt){
            o[mt][0]=0.f;o[mt][1]=0.f;o[mt][2]=0.f;o[mt][3]=0.f;
            bf8 a0 = *(const bf8*)&Pb[(16*mt + l15)*STR + quad*8];
            bf8 a1 = *(const bf8*)&Pb[(16*mt + l15)*STR + 32 + quad*8];
            o[mt] = __builtin_amdgcn_mfma_f32_16x16x32_bf16(a0, bv0, o[mt], 0,0,0);
            o[mt] = __builtin_amdgcn_mfma_f32_16x16x32_bf16(a1, bv1, o[mt], 0,0,0);
        }
    }
    __syncthreads();   // all P6 reads done before ctx overwrites B3

    // ---- P7: ctx -> B3 row-major ----
    #pragma unroll
    for (int mt=0;mt<4;++mt)
        #pragma unroll
        for (int r=0;r<4;++r)
            B3[(16*mt + quad*4 + r)*STR + 16*w + l15] = (short)f2bf(o[mt][r]);
    __syncthreads();

    // ---- P8: out = ctx@oW + ob -> global ----
    {
        f4v c[4];
        #pragma unroll
        for (int nt=0;nt<4;++nt){
            c[nt][0]=obv[nt];c[nt][1]=obv[nt];c[nt][2]=obv[nt];c[nt][3]=obv[nt];
        }
        mmlin(B3, B1, w, l15, quad, c);
        #pragma unroll
        for (int nt=0;nt<4;++nt)
            #pragma unroll
            for (int r=0;r<4;++r)
                out[((size_t)b*64 + 16*w + quad*4 + r)*64 + 16*nt + l15] = c[nt][r];
    }
}

extern "C" void kernel_launch(void* const* d_in, const int* in_sizes, int n_in,
                              void* d_out, int out_size, void* d_ws, size_t ws_size,
                              hipStream_t stream) {
    const int B = in_sizes[0] / (64 * 64);  // 2048

    // workspace carve (2.03 MB): s64 | pattn | WqT | WkT | oWT | E (bf16)
    float* ws_s64 = (float*)d_ws;
    float* ws_pat = ws_s64 + 64;
    u16*   ws_wq  = (u16*)(ws_pat + (size_t)B*4*64);
    u16*   ws_wk  = ws_wq + 4096;
    u16*   ws_ow  = ws_wk + 4096;
    u16*   ws_e   = ws_ow + 4096;

    pre_kernel<<<B + 4, 256, 0, stream>>>(
        (const float*)d_in[1],  (const float*)d_in[2],  (const int*)d_in[3],
        (const float*)d_in[4],  (const float*)d_in[5],
        (const float*)d_in[6],  (const float*)d_in[7],  (const float*)d_in[8],  (const float*)d_in[9],
        (const float*)d_in[10], (const float*)d_in[13], (const float*)d_in[14],
        (const float*)d_in[16], (const float*)d_in[17],
        ws_s64, ws_pat, ws_wq, ws_wk, ws_ow, ws_e, B);

    attn_main_kernel<<<B, 256, 0, stream>>>(
        (const float*)d_in[0],  (const float*)d_in[12], (const float*)d_in[15],
        ws_s64, ws_pat, ws_wq, ws_wk, ws_ow, ws_e,
        (float*)d_out);
}